// Round 9
// baseline (497.221 us; speedup 1.0000x reference)
//
#include <hip/hip_runtime.h>
#include <hip/hip_bf16.h>
#include <hip/hip_fp16.h>

// DKVMN fused pipeline for MI355X (gfx950)
// B=256, T=512, DIM_KEY=256, DIM_VALUE=128, NUM_ITEM=2000
// k0_cvt : f32 tables -> bf16 tables in ws (MFMA operands)
// k1_wea : gather + [Mk|e_W|a_W] GEMM (bf16 MFMA); outputs w (f16 [pos][128])
//          and EA (f16 interleaved [pos][k][{-e, a}])
// k2_scan: scan, M in MFMA B-fragment layout; read = w^T M on the matrix pipe
//          (v-sum inside MFMA accumulate chain; no LDS/barriers/readlane).
//          R9: wave owns 16 k x 128 v -> grid 1024 (batch x k-quarter) =
//          4 waves/SIMD to hide MFMA<->VALU hazards (R8: 2 waves = 59% busy).
// k3_f   : [reads|k] @ f_W^T GEMM + tanh, FUSED predict-dot epilogue -> pd
// k4_pred: out = sigmoid(pd[0]+pd[1]+p_b)

#define T_SEQ 512
#define DK    256
#define DV    128
#define NITEM 2000
#define BT    131072   // 256*512

typedef __attribute__((ext_vector_type(8))) short bf16x8;
typedef __attribute__((ext_vector_type(4))) float f32x4;
typedef _Float16 f16x8 __attribute__((ext_vector_type(8)));

__device__ __forceinline__ float bf2f(unsigned short u) {
    return __uint_as_float(((unsigned int)u) << 16);
}
__device__ __forceinline__ unsigned short f2bf(float x) {   // RNE f32->bf16
    unsigned int u = __float_as_uint(x);
    return (unsigned short)((u + 0x7fffu + ((u >> 16) & 1u)) >> 16);
}
__device__ __forceinline__ unsigned short f2h(float x) {    // f32->f16
    _Float16 h = (_Float16)x;
    return __builtin_bit_cast(unsigned short, h);
}
__device__ __forceinline__ float fast_rcp(float x) { return __builtin_amdgcn_rcpf(x); }
__device__ __forceinline__ float fast_sigmoid(float x) { return fast_rcp(1.f + __expf(-x)); }
__device__ __forceinline__ float fast_tanh(float x) {
    float t = __expf(2.f * x);
    return (t - 1.f) * fast_rcp(t + 1.f);
}
__device__ __forceinline__ f16x8 fma8(f16x8 a, f16x8 b, f16x8 c) {
    return __builtin_elementwise_fma(a, b, c);
}
__device__ __forceinline__ f16x8 splat8(_Float16 x) {
    return (f16x8){x, x, x, x, x, x, x, x};
}
__device__ __forceinline__ _Float16 lo16(unsigned int u) {
    return __builtin_bit_cast(_Float16, (unsigned short)(u & 0xffffu));
}
__device__ __forceinline__ _Float16 hi16(unsigned int u) {
    return __builtin_bit_cast(_Float16, (unsigned short)(u >> 16));
}

// ---------------------------------------------------------------------------
// k0: f32 -> bf16 table conversion (up to 5 tables per launch, y = table id)
// ---------------------------------------------------------------------------
__global__ __launch_bounds__(256) void k0_cvt(
    const float* __restrict__ s0, const float* __restrict__ s1,
    const float* __restrict__ s2, const float* __restrict__ s3,
    const float* __restrict__ s4,
    unsigned short* __restrict__ d0, unsigned short* __restrict__ d1,
    unsigned short* __restrict__ d2, unsigned short* __restrict__ d3,
    unsigned short* __restrict__ d4,
    int n0, int n1, int n2, int n3, int n4)
{
    const float* s; unsigned short* d; int n;
    switch (blockIdx.y) {
        case 0:  s = s0; d = d0; n = n0; break;
        case 1:  s = s1; d = d1; n = n1; break;
        case 2:  s = s2; d = d2; n = n2; break;
        case 3:  s = s3; d = d3; n = n3; break;
        default: s = s4; d = d4; n = n4; break;
    }
    int i4 = (blockIdx.x * 256 + threadIdx.x) * 4;
    if (i4 < n) {
        float4 v = *(const float4*)(s + i4);
        ushort4 o;
        o.x = f2bf(v.x); o.y = f2bf(v.y); o.z = f2bf(v.z); o.w = f2bf(v.w);
        *(ushort4*)(d + i4) = o;
    }
}

// ---------------------------------------------------------------------------
// K1: 128 rows x 128 cols per block, 4 waves stacked by rows.
// n_tile 0 -> w (softmax, f16 [row][128]); 1,2 -> e halves (-sigmoid into EA
// even slots); 3,4 -> a halves (tanh into EA odd slots).
// ---------------------------------------------------------------------------
__global__ __launch_bounds__(256) void k1_wea(
    const int* __restrict__ item_seq, const int* __restrict__ correct_seq,
    const unsigned short* __restrict__ k_bf, const unsigned short* __restrict__ v_bf,
    const unsigned short* __restrict__ Mk_bf,
    const unsigned short* __restrict__ eW_bf, const float* __restrict__ e_b,
    const unsigned short* __restrict__ aW_bf, const float* __restrict__ a_b,
    unsigned short* __restrict__ Wout, unsigned short* __restrict__ EAout)
{
    const int m_tile = blockIdx.x;   // 0..1023
    const int n_tile = blockIdx.y;   // 0..4
    const int tid  = threadIdx.x;
    const int lane = tid & 63;
    const int wv   = tid >> 6;

    __shared__ int idx_s[128];
    __shared__ unsigned short A_s[128 * 40];
    __shared__ unsigned short B_s[128 * 40];

    const unsigned short* Atab = (n_tile == 0) ? k_bf : v_bf;
    const unsigned short* Wtab; int wrow0;
    if (n_tile == 0)      { Wtab = Mk_bf; wrow0 = 0;   }
    else if (n_tile == 1) { Wtab = eW_bf; wrow0 = 0;   }
    else if (n_tile == 2) { Wtab = eW_bf; wrow0 = 128; }
    else if (n_tile == 3) { Wtab = aW_bf; wrow0 = 0;   }
    else                  { Wtab = aW_bf; wrow0 = 128; }

    if (tid < 128) {
        int pos = m_tile * 128 + tid;
        int it = item_seq[pos];
        int co = correct_seq[pos];
        idx_s[tid] = (n_tile == 0) ? it : (it + NITEM * co);
    }
    __syncthreads();

    int myrow[4], myc4[4], myidx[4];
    #pragma unroll
    for (int j = 0; j < 4; ++j) {
        int chunk = tid + 256 * j;
        myrow[j] = chunk >> 3;
        myc4[j]  = chunk & 7;
        myidx[j] = idx_s[myrow[j]];
    }

    f32x4 acc[2][8];
    #pragma unroll
    for (int mi = 0; mi < 2; ++mi)
        #pragma unroll
        for (int ni = 0; ni < 8; ++ni)
            acc[mi][ni] = (f32x4){0.f, 0.f, 0.f, 0.f};

    for (int bk = 0; bk < 8; ++bk) {
        int k0 = bk * 32;
        #pragma unroll
        for (int j = 0; j < 4; ++j) {
            int row = myrow[j], c4 = myc4[j];
            *(ushort4*)&A_s[row * 40 + c4 * 4] =
                *(const ushort4*)(Atab + (long)myidx[j] * DK + k0 + c4 * 4);
            *(ushort4*)&B_s[row * 40 + c4 * 4] =
                *(const ushort4*)(Wtab + (long)(wrow0 + row) * DK + k0 + c4 * 4);
        }
        __syncthreads();

        const int kq = lane >> 4;   // k-slot 0..3 (8 bf16 each)
        const int rr = lane & 15;
        bf16x8 af[2], bfr[8];
        #pragma unroll
        for (int mi = 0; mi < 2; ++mi)
            af[mi] = *(const bf16x8*)&A_s[(wv * 32 + mi * 16 + rr) * 40 + kq * 8];
        #pragma unroll
        for (int ni = 0; ni < 8; ++ni)
            bfr[ni] = *(const bf16x8*)&B_s[(ni * 16 + rr) * 40 + kq * 8];
        #pragma unroll
        for (int ni = 0; ni < 8; ++ni)
            #pragma unroll
            for (int mi = 0; mi < 2; ++mi)
                acc[mi][ni] = __builtin_amdgcn_mfma_f32_16x16x32_bf16(
                    af[mi], bfr[ni], acc[mi][ni], 0, 0, 0);
        __syncthreads();
    }

    // C/D layout: col = lane&15, row = (lane>>4)*4 + reg (m89-verified)
    const int rowbase = m_tile * 128 + wv * 32;
    const int cgrp = lane >> 4;
    const int cc   = lane & 15;

    if (n_tile == 0) {
        #pragma unroll
        for (int mi = 0; mi < 2; ++mi) {
            #pragma unroll
            for (int i = 0; i < 4; ++i) {
                float m = -1e30f;
                #pragma unroll
                for (int ni = 0; ni < 8; ++ni) m = fmaxf(m, acc[mi][ni][i]);
                m = fmaxf(m, __shfl_xor(m, 1));
                m = fmaxf(m, __shfl_xor(m, 2));
                m = fmaxf(m, __shfl_xor(m, 4));
                m = fmaxf(m, __shfl_xor(m, 8));
                float p[8]; float s = 0.f;
                #pragma unroll
                for (int ni = 0; ni < 8; ++ni) { p[ni] = __expf(acc[mi][ni][i] - m); s += p[ni]; }
                s += __shfl_xor(s, 1); s += __shfl_xor(s, 2);
                s += __shfl_xor(s, 4); s += __shfl_xor(s, 8);
                float inv = fast_rcp(s);
                int row = rowbase + mi * 16 + cgrp * 4 + i;
                #pragma unroll
                for (int ni = 0; ni < 8; ++ni)
                    Wout[(long)row * 128 + ni * 16 + cc] = f2h(p[ni] * inv);
            }
        }
    } else {
        const bool is_e = (n_tile <= 2);
        const float* bias = is_e ? e_b : a_b;
        const int colbase = (is_e ? (n_tile - 1) : (n_tile - 3)) * 128;
        const int sel = is_e ? 0 : 1;
        #pragma unroll
        for (int ni = 0; ni < 8; ++ni) {
            int colp = colbase + ni * 16 + cc;
            float bb = bias[colp];
            #pragma unroll
            for (int mi = 0; mi < 2; ++mi) {
                #pragma unroll
                for (int i = 0; i < 4; ++i) {
                    int row = rowbase + mi * 16 + cgrp * 4 + i;
                    float x = acc[mi][ni][i] + bb;
                    float v = is_e ? -fast_sigmoid(x) : fast_tanh(x);  // e stored negated
                    EAout[(long)row * 512 + 2 * colp + sel] = f2h(v);
                }
            }
        }
    }
}

// ---------------------------------------------------------------------------
// K2: scan, MFMA-offloaded reads. 1024 blocks = (batch, k-quarter), 256 thr
// = 4 waves (4 blocks/CU -> 4 waves/SIMD), 0 LDS, 0 barriers.
// Wave owns 128 v x 16 k (kw = kqd*64 + wv*16). M in B-fragment layout:
//   Mb[vt][j] = M[v = vt*32 + (lane>>4)*8 + j][k = kw + (lane&15)]
// Per step: 4 w-frag loads (dwordx4; A-operand AND packed update multiplier),
// 1 EA dword; 4 accumulating MFMAs -> read (pre-update M, D only stored);
// VALU update = 2 fma8 per vt. Dist-2 prefetch, named sets.
// ---------------------------------------------------------------------------
__global__ __launch_bounds__(256, 4) void k2_scan(
    const float* __restrict__ Mv0,
    const unsigned short* __restrict__ Wws,
    const unsigned int* __restrict__ EAws,
    unsigned short* __restrict__ Rws)
{
    const int b    = blockIdx.x >> 2;
    const int kqd  = blockIdx.x & 3;
    const int tid  = threadIdx.x;
    const int lane = tid & 63;
    const int wv   = tid >> 6;          // 0..3
    const int row16 = lane & 15;
    const int oct   = lane >> 4;        // v-octet within each 32-v tile
    const int kw    = kqd * 64 + wv * 16;

    // M fragments (one-time f32 gather)
    f16x8 Mb[4];
    #pragma unroll
    for (int vt = 0; vt < 4; ++vt) {
        f16x8 m;
        #pragma unroll
        for (int j = 0; j < 8; ++j)
            m[j] = (_Float16)Mv0[(vt * 32 + oct * 8 + j) * DK + kw + row16];
        Mb[vt] = m;
    }

    const long pos0 = (long)b * T_SEQ;

    // dist-2 prefetch sets
    uint4 wfA[4], wfB[4];
    unsigned int eaA, eaB;
    {
        const unsigned short* wq = Wws + pos0 * 128 + oct * 8;
        wfA[0] = *(const uint4*)(wq);      wfA[1] = *(const uint4*)(wq + 32);
        wfA[2] = *(const uint4*)(wq + 64); wfA[3] = *(const uint4*)(wq + 96);
        wq += 128;
        wfB[0] = *(const uint4*)(wq);      wfB[1] = *(const uint4*)(wq + 32);
        wfB[2] = *(const uint4*)(wq + 64); wfB[3] = *(const uint4*)(wq + 96);
        eaA = EAws[pos0 * 256 + kw + row16];
        eaB = EAws[(pos0 + 1) * 256 + kw + row16];
    }

#define K2_STEP(T, WF, EA)                                                     \
    {                                                                          \
        const uint4 w0 = WF[0], w1 = WF[1], w2 = WF[2], w3 = WF[3];            \
        const unsigned int ea = EA;                                            \
        {   /* issue t+2 loads */                                              \
            long pn = pos0 + ((T) + 2 < T_SEQ ? (T) + 2 : T_SEQ - 1);          \
            const unsigned short* wq = Wws + pn * 128 + oct * 8;               \
            WF[0] = *(const uint4*)(wq);                                       \
            WF[1] = *(const uint4*)(wq + 32);                                  \
            WF[2] = *(const uint4*)(wq + 64);                                  \
            WF[3] = *(const uint4*)(wq + 96);                                  \
            EA = EAws[pn * 256 + kw + row16];                                  \
        }                                                                      \
        const f16x8 w80 = __builtin_bit_cast(f16x8, w0);                       \
        const f16x8 w81 = __builtin_bit_cast(f16x8, w1);                       \
        const f16x8 w82 = __builtin_bit_cast(f16x8, w2);                       \
        const f16x8 w83 = __builtin_bit_cast(f16x8, w3);                       \
        /* read on the matrix pipe, pre-update M (D not consumed by loop) */   \
        f32x4 D = (f32x4){0.f, 0.f, 0.f, 0.f};                                 \
        D = __builtin_amdgcn_mfma_f32_16x16x32_f16(w80, Mb[0], D, 0, 0, 0);    \
        D = __builtin_amdgcn_mfma_f32_16x16x32_f16(w81, Mb[1], D, 0, 0, 0);    \
        D = __builtin_amdgcn_mfma_f32_16x16x32_f16(w82, Mb[2], D, 0, 0, 0);    \
        D = __builtin_amdgcn_mfma_f32_16x16x32_f16(w83, Mb[3], D, 0, 0, 0);    \
        /* VALU update: M = M + w*(a - e*M); EA holds {-e, a} */               \
        const f16x8 ne8 = splat8(lo16(ea)), a8 = splat8(hi16(ea));             \
        Mb[0] = fma8(w80, fma8(ne8, Mb[0], a8), Mb[0]);                        \
        Mb[1] = fma8(w81, fma8(ne8, Mb[1], a8), Mb[1]);                        \
        Mb[2] = fma8(w82, fma8(ne8, Mb[2], a8), Mb[2]);                        \
        Mb[3] = fma8(w83, fma8(ne8, Mb[3], a8), Mb[3]);                        \
        /* store read: all D rows identical (A rows = w for every row) */      \
        if (lane < 16)                                                         \
            Rws[(pos0 + (T)) * 256 + kw + lane] = f2bf(D[0]);                  \
    }

    for (int t = 0; t < T_SEQ; t += 2) {
        K2_STEP(t,     wfA, eaA)
        K2_STEP(t + 1, wfB, eaB)
    }
#undef K2_STEP
}

// ---------------------------------------------------------------------------
// K3: f = tanh([reads | k] @ f_W^T + f_b), fused predict-dot epilogue:
// writes pd[nt][row] = sum_{cols in tile} f * p_W  (f itself never stored).
// ---------------------------------------------------------------------------
__global__ __launch_bounds__(256) void k3_f(
    const int* __restrict__ item_seq,
    const unsigned short* __restrict__ k_bf,
    const unsigned short* __restrict__ fW_bf, const float* __restrict__ f_b,
    const float* __restrict__ p_W,
    const unsigned short* __restrict__ Rws,
    float* __restrict__ pd)
{
    const int m_tile = blockIdx.x;   // 0..1023
    const int nt  = blockIdx.y;      // 0..1
    const int tid = threadIdx.x;
    const int lane = tid & 63;
    const int wv   = tid >> 6;

    __shared__ int idx_s[128];
    __shared__ unsigned short A_s[128 * 40];
    __shared__ unsigned short B_s[128 * 40];

    if (tid < 128) idx_s[tid] = item_seq[m_tile * 128 + tid];
    __syncthreads();

    int myrow[4], myc4[4], myidx[4];
    #pragma unroll
    for (int j = 0; j < 4; ++j) {
        int chunk = tid + 256 * j;
        myrow[j] = chunk >> 3;
        myc4[j]  = chunk & 7;
        myidx[j] = idx_s[myrow[j]];
    }

    f32x4 acc[2][8];
    #pragma unroll
    for (int mi = 0; mi < 2; ++mi)
        #pragma unroll
        for (int ni = 0; ni < 8; ++ni)
            acc[mi][ni] = (f32x4){0.f, 0.f, 0.f, 0.f};

    for (int bk = 0; bk < 16; ++bk) {
        int k0 = bk * 32;
        #pragma unroll
        for (int j = 0; j < 4; ++j) {
            int row = myrow[j], c4 = myc4[j];
            ushort4 ap;
            if (k0 < 256) {
                long pos = (long)m_tile * 128 + row;
                ap = *(const ushort4*)(Rws + pos * 256 + k0 + c4 * 4);
            } else {
                ap = *(const ushort4*)(k_bf + (long)myidx[j] * DK + (k0 - 256) + c4 * 4);
            }
            *(ushort4*)&A_s[row * 40 + c4 * 4] = ap;
            *(ushort4*)&B_s[row * 40 + c4 * 4] =
                *(const ushort4*)(fW_bf + (long)(nt * 128 + row) * 512 + k0 + c4 * 4);
        }
        __syncthreads();

        const int kq = lane >> 4;
        const int rr = lane & 15;
        bf16x8 af[2], bfr[8];
        #pragma unroll
        for (int mi = 0; mi < 2; ++mi)
            af[mi] = *(const bf16x8*)&A_s[(wv * 32 + mi * 16 + rr) * 40 + kq * 8];
        #pragma unroll
        for (int ni = 0; ni < 8; ++ni)
            bfr[ni] = *(const bf16x8*)&B_s[(ni * 16 + rr) * 40 + kq * 8];
        #pragma unroll
        for (int ni = 0; ni < 8; ++ni)
            #pragma unroll
            for (int mi = 0; mi < 2; ++mi)
                acc[mi][ni] = __builtin_amdgcn_mfma_f32_16x16x32_bf16(
                    af[mi], bfr[ni], acc[mi][ni], 0, 0, 0);
        __syncthreads();
    }

    const int rowbase = m_tile * 128 + wv * 32;
    const int cgrp = lane >> 4;
    const int cc   = lane & 15;

    float pw[8];
    #pragma unroll
    for (int ni = 0; ni < 8; ++ni) pw[ni] = p_W[nt * 128 + ni * 16 + cc];

    float s[2][4] = {{0.f,0.f,0.f,0.f},{0.f,0.f,0.f,0.f}};
    #pragma unroll
    for (int ni = 0; ni < 8; ++ni) {
        float bb = f_b[nt * 128 + ni * 16 + cc];
        #pragma unroll
        for (int mi = 0; mi < 2; ++mi)
            #pragma unroll
            for (int i = 0; i < 4; ++i)
                s[mi][i] += fast_tanh(acc[mi][ni][i] + bb) * pw[ni];
    }
    // reduce across the 16-lane col group
    #pragma unroll
    for (int mi = 0; mi < 2; ++mi)
        #pragma unroll
        for (int i = 0; i < 4; ++i) {
            float v = s[mi][i];
            v += __shfl_xor(v, 1); v += __shfl_xor(v, 2);
            v += __shfl_xor(v, 4); v += __shfl_xor(v, 8);
            s[mi][i] = v;
        }
    if (cc == 0) {
        #pragma unroll
        for (int mi = 0; mi < 2; ++mi)
            #pragma unroll
            for (int i = 0; i < 4; ++i)
                pd[(long)nt * BT + rowbase + mi * 16 + cgrp * 4 + i] = s[mi][i];
    }
}

// ---------------------------------------------------------------------------
// K4: out = sigmoid(pd[0][row] + pd[1][row] + p_b)
// ---------------------------------------------------------------------------
__global__ __launch_bounds__(256) void k4_pred(
    const float* __restrict__ pd, const float* __restrict__ p_b,
    float* __restrict__ out)
{
    int i = blockIdx.x * 256 + threadIdx.x;
    out[i] = fast_sigmoid(pd[i] + pd[BT + i] + p_b[0]);
}

// ---------------------------------------------------------------------------
extern "C" void kernel_launch(void* const* d_in, const int* in_sizes, int n_in,
                              void* d_out, int out_size, void* d_ws, size_t ws_size,
                              hipStream_t stream)
{
    const int*   item_seq    = (const int*)d_in[0];
    const int*   correct_seq = (const int*)d_in[1];
    const float* k_emb = (const float*)d_in[2];
    const float* v_emb = (const float*)d_in[3];
    const float* Mk    = (const float*)d_in[4];
    const float* Mv0   = (const float*)d_in[5];
    const float* e_W   = (const float*)d_in[6];
    const float* e_b   = (const float*)d_in[7];
    const float* a_W   = (const float*)d_in[8];
    const float* a_b   = (const float*)d_in[9];
    const float* f_W   = (const float*)d_in[10];
    const float* f_b   = (const float*)d_in[11];
    const float* p_W   = (const float*)d_in[12];
    const float* p_b   = (const float*)d_in[13];
    float* out = (float*)d_out;

    // ws layout (bytes):
    //   [0,   32M)  Wws  w f16 [BT][128]       (k3 tables re-use after k2)
    //   [32M, 160M) EA   f16 [BT][256][{-e,a}] (dead after k2; pd parked here)
    //   [160M,224M) Rws  reads bf16 [BT][256]  (k1 bf16 tables live here pre-k2)
    char* ws = (char*)d_ws;
    unsigned short* Wws = (unsigned short*)(ws);
    unsigned short* EAo = (unsigned short*)(ws + 33554432ll);
    unsigned int*   EAi = (unsigned int*)(ws + 33554432ll);
    unsigned short* Rws = (unsigned short*)(ws + 167772160ll);
    float*          pd  = (float*)(ws + 33554432ll);   // EA region, dead after k2

    // k1-phase bf16 tables, parked in the (still dead) Rws region
    unsigned short* kA_bf = Rws;                 // 512000
    unsigned short* v_bf  = Rws + 512000;        // 1024000
    unsigned short* Mk_bf = Rws + 1536000;       // 32768
    unsigned short* eW_bf = Rws + 1568768;       // 65536
    unsigned short* aW_bf = Rws + 1634304;       // 65536
    // k3-phase bf16 tables, parked in the (dead after k2) Wws region
    unsigned short* k3_bf = Wws;                 // 512000
    unsigned short* fW_bf = Wws + 512000;        // 131072

    k0_cvt<<<dim3(1000, 5), dim3(256), 0, stream>>>(
        k_emb, v_emb, Mk, e_W, a_W,
        kA_bf, v_bf, Mk_bf, eW_bf, aW_bf,
        512000, 1024000, 32768, 65536, 65536);

    k1_wea<<<dim3(1024, 5), dim3(256), 0, stream>>>(
        item_seq, correct_seq, kA_bf, v_bf, Mk_bf, eW_bf, e_b, aW_bf, a_b,
        Wws, EAo);

    k2_scan<<<dim3(1024), dim3(256), 0, stream>>>(Mv0, Wws, EAi, Rws);

    k0_cvt<<<dim3(500, 2), dim3(256), 0, stream>>>(
        k_emb, f_W, nullptr, nullptr, nullptr,
        k3_bf, fW_bf, nullptr, nullptr, nullptr,
        512000, 131072, 0, 0, 0);

    k3_f<<<dim3(1024, 2), dim3(256), 0, stream>>>(
        item_seq, k3_bf, fW_bf, f_b, p_W, Rws, pd);

    k4_pred<<<dim3(512), dim3(256), 0, stream>>>(pd, p_b, out);
}

// Round 10
// 489.653 us; speedup vs baseline: 1.0155x; 1.0155x over previous
//
#include <hip/hip_runtime.h>
#include <hip/hip_bf16.h>
#include <hip/hip_fp16.h>

// DKVMN fused pipeline for MI355X (gfx950)
// B=256, T=512, DIM_KEY=256, DIM_VALUE=128, NUM_ITEM=2000
// k0_cvt : f32 tables -> bf16 tables in ws (MFMA operands)
// k1_wea : gather + [Mk|e_W|a_W] GEMM (bf16 MFMA); outputs w (f16 [pos][128])
//          and EA (f16 interleaved [pos][k][{-e, a}])
// k2_scan: scan, M in MFMA B-fragment layout; read = w^T M on the matrix pipe.
//          R10: TWO BATCHES PER WAVE (independent chains -> in-wave ILP fills
//          MFMA/VALU hazards; R9 lesson: extra waves via k-split duplicate
//          O(V) w-loads, extra batches don't). 256 blocks = 1/CU, 1 wave/SIMD,
//          launch_bounds(256,1) for the ~170-VGPR state. 0 LDS, 0 barriers.
// k3_f   : [reads|k] @ f_W^T GEMM + tanh, FUSED predict-dot epilogue -> pd
// k4_pred: out = sigmoid(pd[0]+pd[1]+p_b)

#define T_SEQ 512
#define DK    256
#define DV    128
#define NITEM 2000
#define BT    131072   // 256*512

typedef __attribute__((ext_vector_type(8))) short bf16x8;
typedef __attribute__((ext_vector_type(4))) float f32x4;
typedef _Float16 f16x8 __attribute__((ext_vector_type(8)));

__device__ __forceinline__ float bf2f(unsigned short u) {
    return __uint_as_float(((unsigned int)u) << 16);
}
__device__ __forceinline__ unsigned short f2bf(float x) {   // RNE f32->bf16
    unsigned int u = __float_as_uint(x);
    return (unsigned short)((u + 0x7fffu + ((u >> 16) & 1u)) >> 16);
}
__device__ __forceinline__ unsigned short f2h(float x) {    // f32->f16
    _Float16 h = (_Float16)x;
    return __builtin_bit_cast(unsigned short, h);
}
__device__ __forceinline__ float fast_rcp(float x) { return __builtin_amdgcn_rcpf(x); }
__device__ __forceinline__ float fast_sigmoid(float x) { return fast_rcp(1.f + __expf(-x)); }
__device__ __forceinline__ float fast_tanh(float x) {
    float t = __expf(2.f * x);
    return (t - 1.f) * fast_rcp(t + 1.f);
}
__device__ __forceinline__ f16x8 fma8(f16x8 a, f16x8 b, f16x8 c) {
    return __builtin_elementwise_fma(a, b, c);
}
__device__ __forceinline__ f16x8 splat8(_Float16 x) {
    return (f16x8){x, x, x, x, x, x, x, x};
}
__device__ __forceinline__ _Float16 lo16(unsigned int u) {
    return __builtin_bit_cast(_Float16, (unsigned short)(u & 0xffffu));
}
__device__ __forceinline__ _Float16 hi16(unsigned int u) {
    return __builtin_bit_cast(_Float16, (unsigned short)(u >> 16));
}

// ---------------------------------------------------------------------------
// k0: f32 -> bf16 table conversion (up to 5 tables per launch, y = table id)
// ---------------------------------------------------------------------------
__global__ __launch_bounds__(256) void k0_cvt(
    const float* __restrict__ s0, const float* __restrict__ s1,
    const float* __restrict__ s2, const float* __restrict__ s3,
    const float* __restrict__ s4,
    unsigned short* __restrict__ d0, unsigned short* __restrict__ d1,
    unsigned short* __restrict__ d2, unsigned short* __restrict__ d3,
    unsigned short* __restrict__ d4,
    int n0, int n1, int n2, int n3, int n4)
{
    const float* s; unsigned short* d; int n;
    switch (blockIdx.y) {
        case 0:  s = s0; d = d0; n = n0; break;
        case 1:  s = s1; d = d1; n = n1; break;
        case 2:  s = s2; d = d2; n = n2; break;
        case 3:  s = s3; d = d3; n = n3; break;
        default: s = s4; d = d4; n = n4; break;
    }
    int i4 = (blockIdx.x * 256 + threadIdx.x) * 4;
    if (i4 < n) {
        float4 v = *(const float4*)(s + i4);
        ushort4 o;
        o.x = f2bf(v.x); o.y = f2bf(v.y); o.z = f2bf(v.z); o.w = f2bf(v.w);
        *(ushort4*)(d + i4) = o;
    }
}

// ---------------------------------------------------------------------------
// K1: 128 rows x 128 cols per block, 4 waves stacked by rows.
// n_tile 0 -> w (softmax, f16 [row][128]); 1,2 -> e halves (-sigmoid into EA
// even slots); 3,4 -> a halves (tanh into EA odd slots).
// ---------------------------------------------------------------------------
__global__ __launch_bounds__(256) void k1_wea(
    const int* __restrict__ item_seq, const int* __restrict__ correct_seq,
    const unsigned short* __restrict__ k_bf, const unsigned short* __restrict__ v_bf,
    const unsigned short* __restrict__ Mk_bf,
    const unsigned short* __restrict__ eW_bf, const float* __restrict__ e_b,
    const unsigned short* __restrict__ aW_bf, const float* __restrict__ a_b,
    unsigned short* __restrict__ Wout, unsigned short* __restrict__ EAout)
{
    const int m_tile = blockIdx.x;   // 0..1023
    const int n_tile = blockIdx.y;   // 0..4
    const int tid  = threadIdx.x;
    const int lane = tid & 63;
    const int wv   = tid >> 6;

    __shared__ int idx_s[128];
    __shared__ unsigned short A_s[128 * 40];
    __shared__ unsigned short B_s[128 * 40];

    const unsigned short* Atab = (n_tile == 0) ? k_bf : v_bf;
    const unsigned short* Wtab; int wrow0;
    if (n_tile == 0)      { Wtab = Mk_bf; wrow0 = 0;   }
    else if (n_tile == 1) { Wtab = eW_bf; wrow0 = 0;   }
    else if (n_tile == 2) { Wtab = eW_bf; wrow0 = 128; }
    else if (n_tile == 3) { Wtab = aW_bf; wrow0 = 0;   }
    else                  { Wtab = aW_bf; wrow0 = 128; }

    if (tid < 128) {
        int pos = m_tile * 128 + tid;
        int it = item_seq[pos];
        int co = correct_seq[pos];
        idx_s[tid] = (n_tile == 0) ? it : (it + NITEM * co);
    }
    __syncthreads();

    int myrow[4], myc4[4], myidx[4];
    #pragma unroll
    for (int j = 0; j < 4; ++j) {
        int chunk = tid + 256 * j;
        myrow[j] = chunk >> 3;
        myc4[j]  = chunk & 7;
        myidx[j] = idx_s[myrow[j]];
    }

    f32x4 acc[2][8];
    #pragma unroll
    for (int mi = 0; mi < 2; ++mi)
        #pragma unroll
        for (int ni = 0; ni < 8; ++ni)
            acc[mi][ni] = (f32x4){0.f, 0.f, 0.f, 0.f};

    for (int bk = 0; bk < 8; ++bk) {
        int k0 = bk * 32;
        #pragma unroll
        for (int j = 0; j < 4; ++j) {
            int row = myrow[j], c4 = myc4[j];
            *(ushort4*)&A_s[row * 40 + c4 * 4] =
                *(const ushort4*)(Atab + (long)myidx[j] * DK + k0 + c4 * 4);
            *(ushort4*)&B_s[row * 40 + c4 * 4] =
                *(const ushort4*)(Wtab + (long)(wrow0 + row) * DK + k0 + c4 * 4);
        }
        __syncthreads();

        const int kq = lane >> 4;   // k-slot 0..3 (8 bf16 each)
        const int rr = lane & 15;
        bf16x8 af[2], bfr[8];
        #pragma unroll
        for (int mi = 0; mi < 2; ++mi)
            af[mi] = *(const bf16x8*)&A_s[(wv * 32 + mi * 16 + rr) * 40 + kq * 8];
        #pragma unroll
        for (int ni = 0; ni < 8; ++ni)
            bfr[ni] = *(const bf16x8*)&B_s[(ni * 16 + rr) * 40 + kq * 8];
        #pragma unroll
        for (int ni = 0; ni < 8; ++ni)
            #pragma unroll
            for (int mi = 0; mi < 2; ++mi)
                acc[mi][ni] = __builtin_amdgcn_mfma_f32_16x16x32_bf16(
                    af[mi], bfr[ni], acc[mi][ni], 0, 0, 0);
        __syncthreads();
    }

    // C/D layout: col = lane&15, row = (lane>>4)*4 + reg (m89-verified)
    const int rowbase = m_tile * 128 + wv * 32;
    const int cgrp = lane >> 4;
    const int cc   = lane & 15;

    if (n_tile == 0) {
        #pragma unroll
        for (int mi = 0; mi < 2; ++mi) {
            #pragma unroll
            for (int i = 0; i < 4; ++i) {
                float m = -1e30f;
                #pragma unroll
                for (int ni = 0; ni < 8; ++ni) m = fmaxf(m, acc[mi][ni][i]);
                m = fmaxf(m, __shfl_xor(m, 1));
                m = fmaxf(m, __shfl_xor(m, 2));
                m = fmaxf(m, __shfl_xor(m, 4));
                m = fmaxf(m, __shfl_xor(m, 8));
                float p[8]; float s = 0.f;
                #pragma unroll
                for (int ni = 0; ni < 8; ++ni) { p[ni] = __expf(acc[mi][ni][i] - m); s += p[ni]; }
                s += __shfl_xor(s, 1); s += __shfl_xor(s, 2);
                s += __shfl_xor(s, 4); s += __shfl_xor(s, 8);
                float inv = fast_rcp(s);
                int row = rowbase + mi * 16 + cgrp * 4 + i;
                #pragma unroll
                for (int ni = 0; ni < 8; ++ni)
                    Wout[(long)row * 128 + ni * 16 + cc] = f2h(p[ni] * inv);
            }
        }
    } else {
        const bool is_e = (n_tile <= 2);
        const float* bias = is_e ? e_b : a_b;
        const int colbase = (is_e ? (n_tile - 1) : (n_tile - 3)) * 128;
        const int sel = is_e ? 0 : 1;
        #pragma unroll
        for (int ni = 0; ni < 8; ++ni) {
            int colp = colbase + ni * 16 + cc;
            float bb = bias[colp];
            #pragma unroll
            for (int mi = 0; mi < 2; ++mi) {
                #pragma unroll
                for (int i = 0; i < 4; ++i) {
                    int row = rowbase + mi * 16 + cgrp * 4 + i;
                    float x = acc[mi][ni][i] + bb;
                    float v = is_e ? -fast_sigmoid(x) : fast_tanh(x);  // e stored negated
                    EAout[(long)row * 512 + 2 * colp + sel] = f2h(v);
                }
            }
        }
    }
}

// ---------------------------------------------------------------------------
// K2: scan, MFMA-offloaded reads, TWO batches per wave. 256 blocks =
// (batch-pair, k-half) = 1 block/CU, 256 thr = 4 waves = 1 wave/SIMD.
// Wave owns 128 v x 32 k for batches b0=2bp and b1=2bp+1 (independent
// dependency chains -> ILP fills MFMA read-hazard + D-chain bubbles).
// M in B-fragment layout of mfma_f32_16x16x32_f16:
//   Mb[vt][kt][j] = M[v = vt*32 + (lane>>4)*8 + j][k = kw + kt*16 + (lane&15)]
// Per batch per step: 4 w-frag loads (A-operand AND update multiplier),
// 2 EA dwords, 8 accumulating MFMAs (read, pre-update M), 16 fma8 update.
// Dist-2 prefetch, named sets. 0 LDS, 0 barriers.
// ---------------------------------------------------------------------------
__global__ __launch_bounds__(256, 1) void k2_scan(
    const float* __restrict__ Mv0,
    const unsigned short* __restrict__ Wws,
    const unsigned int* __restrict__ EAws,
    unsigned short* __restrict__ Rws)
{
    const int bp   = blockIdx.x >> 1;   // batch pair 0..127
    const int kh   = blockIdx.x & 1;
    const int tid  = threadIdx.x;
    const int lane = tid & 63;
    const int wv   = tid >> 6;          // 0..3
    const int row16 = lane & 15;
    const int oct   = lane >> 4;        // v-octet within each 32-v tile
    const int kw    = kh * 128 + wv * 32;

    // M fragments: identical init for both batches (Mv0 broadcast over batch)
    f16x8 Mb0[4][2], Mb1[4][2];
    #pragma unroll
    for (int vt = 0; vt < 4; ++vt)
        #pragma unroll
        for (int kt = 0; kt < 2; ++kt) {
            f16x8 m;
            #pragma unroll
            for (int j = 0; j < 8; ++j)
                m[j] = (_Float16)Mv0[(vt * 32 + oct * 8 + j) * DK + kw + kt * 16 + row16];
            Mb0[vt][kt] = m;
            Mb1[vt][kt] = m;
        }

    const long p0 = (long)(bp * 2)     * T_SEQ;
    const long p1 = (long)(bp * 2 + 1) * T_SEQ;

    // dist-2 prefetch sets, per batch (named arrays, constant indices only)
    uint4 wfA0[4], wfB0[4], wfA1[4], wfB1[4];
    unsigned int eaA00, eaA01, eaB00, eaB01;
    unsigned int eaA10, eaA11, eaB10, eaB11;
    {
        const unsigned short* wq = Wws + p0 * 128 + oct * 8;
        wfA0[0] = *(const uint4*)(wq);      wfA0[1] = *(const uint4*)(wq + 32);
        wfA0[2] = *(const uint4*)(wq + 64); wfA0[3] = *(const uint4*)(wq + 96);
        wq += 128;
        wfB0[0] = *(const uint4*)(wq);      wfB0[1] = *(const uint4*)(wq + 32);
        wfB0[2] = *(const uint4*)(wq + 64); wfB0[3] = *(const uint4*)(wq + 96);
        wq = Wws + p1 * 128 + oct * 8;
        wfA1[0] = *(const uint4*)(wq);      wfA1[1] = *(const uint4*)(wq + 32);
        wfA1[2] = *(const uint4*)(wq + 64); wfA1[3] = *(const uint4*)(wq + 96);
        wq += 128;
        wfB1[0] = *(const uint4*)(wq);      wfB1[1] = *(const uint4*)(wq + 32);
        wfB1[2] = *(const uint4*)(wq + 64); wfB1[3] = *(const uint4*)(wq + 96);
        eaA00 = EAws[p0 * 256 + kw + row16];
        eaA01 = EAws[p0 * 256 + kw + 16 + row16];
        eaB00 = EAws[(p0 + 1) * 256 + kw + row16];
        eaB01 = EAws[(p0 + 1) * 256 + kw + 16 + row16];
        eaA10 = EAws[p1 * 256 + kw + row16];
        eaA11 = EAws[p1 * 256 + kw + 16 + row16];
        eaB10 = EAws[(p1 + 1) * 256 + kw + row16];
        eaB11 = EAws[(p1 + 1) * 256 + kw + 16 + row16];
    }

#define K2_STEP(T, POS0, WF, EA0, EA1, MB)                                     \
    {                                                                          \
        const uint4 w0 = WF[0], w1 = WF[1], w2 = WF[2], w3 = WF[3];            \
        const unsigned int ea0 = EA0, ea1 = EA1;                               \
        {   /* issue t+2 loads */                                              \
            long pn = (POS0) + ((T) + 2 < T_SEQ ? (T) + 2 : T_SEQ - 1);        \
            const unsigned short* wq = Wws + pn * 128 + oct * 8;               \
            WF[0] = *(const uint4*)(wq);                                       \
            WF[1] = *(const uint4*)(wq + 32);                                  \
            WF[2] = *(const uint4*)(wq + 64);                                  \
            WF[3] = *(const uint4*)(wq + 96);                                  \
            EA0 = EAws[pn * 256 + kw + row16];                                 \
            EA1 = EAws[pn * 256 + kw + 16 + row16];                            \
        }                                                                      \
        const f16x8 w80 = __builtin_bit_cast(f16x8, w0);                       \
        const f16x8 w81 = __builtin_bit_cast(f16x8, w1);                       \
        const f16x8 w82 = __builtin_bit_cast(f16x8, w2);                       \
        const f16x8 w83 = __builtin_bit_cast(f16x8, w3);                       \
        /* read on the matrix pipe, pre-update M (D not consumed by loop) */   \
        f32x4 D0 = (f32x4){0.f, 0.f, 0.f, 0.f};                                \
        f32x4 D1 = (f32x4){0.f, 0.f, 0.f, 0.f};                                \
        D0 = __builtin_amdgcn_mfma_f32_16x16x32_f16(w80, MB[0][0], D0, 0,0,0); \
        D0 = __builtin_amdgcn_mfma_f32_16x16x32_f16(w81, MB[1][0], D0, 0,0,0); \
        D0 = __builtin_amdgcn_mfma_f32_16x16x32_f16(w82, MB[2][0], D0, 0,0,0); \
        D0 = __builtin_amdgcn_mfma_f32_16x16x32_f16(w83, MB[3][0], D0, 0,0,0); \
        D1 = __builtin_amdgcn_mfma_f32_16x16x32_f16(w80, MB[0][1], D1, 0,0,0); \
        D1 = __builtin_amdgcn_mfma_f32_16x16x32_f16(w81, MB[1][1], D1, 0,0,0); \
        D1 = __builtin_amdgcn_mfma_f32_16x16x32_f16(w82, MB[2][1], D1, 0,0,0); \
        D1 = __builtin_amdgcn_mfma_f32_16x16x32_f16(w83, MB[3][1], D1, 0,0,0); \
        /* VALU update: M = M + w*(a - e*M); EA holds {-e, a} */               \
        const f16x8 ne80 = splat8(lo16(ea0)), a80 = splat8(hi16(ea0));         \
        const f16x8 ne81 = splat8(lo16(ea1)), a81 = splat8(hi16(ea1));         \
        MB[0][0] = fma8(w80, fma8(ne80, MB[0][0], a80), MB[0][0]);             \
        MB[1][0] = fma8(w81, fma8(ne80, MB[1][0], a80), MB[1][0]);             \
        MB[2][0] = fma8(w82, fma8(ne80, MB[2][0], a80), MB[2][0]);             \
        MB[3][0] = fma8(w83, fma8(ne80, MB[3][0], a80), MB[3][0]);             \
        MB[0][1] = fma8(w80, fma8(ne81, MB[0][1], a81), MB[0][1]);             \
        MB[1][1] = fma8(w81, fma8(ne81, MB[1][1], a81), MB[1][1]);             \
        MB[2][1] = fma8(w82, fma8(ne81, MB[2][1], a81), MB[2][1]);             \
        MB[3][1] = fma8(w83, fma8(ne81, MB[3][1], a81), MB[3][1]);             \
        /* store read: all D rows identical (A rows = w for every row) */      \
        if (lane < 16) {                                                       \
            unsigned short* rp = Rws + ((POS0) + (T)) * 256 + kw + lane;       \
            rp[0]  = f2bf(D0[0]);                                              \
            rp[16] = f2bf(D1[0]);                                              \
        }                                                                      \
    }

    for (int t = 0; t < T_SEQ; t += 2) {
        K2_STEP(t,     p0, wfA0, eaA00, eaA01, Mb0)
        K2_STEP(t,     p1, wfA1, eaA10, eaA11, Mb1)
        K2_STEP(t + 1, p0, wfB0, eaB00, eaB01, Mb0)
        K2_STEP(t + 1, p1, wfB1, eaB10, eaB11, Mb1)
    }
#undef K2_STEP
}

// ---------------------------------------------------------------------------
// K3: f = tanh([reads | k] @ f_W^T + f_b), fused predict-dot epilogue:
// writes pd[nt][row] = sum_{cols in tile} f * p_W  (f itself never stored).
// ---------------------------------------------------------------------------
__global__ __launch_bounds__(256) void k3_f(
    const int* __restrict__ item_seq,
    const unsigned short* __restrict__ k_bf,
    const unsigned short* __restrict__ fW_bf, const float* __restrict__ f_b,
    const float* __restrict__ p_W,
    const unsigned short* __restrict__ Rws,
    float* __restrict__ pd)
{
    const int m_tile = blockIdx.x;   // 0..1023
    const int nt  = blockIdx.y;      // 0..1
    const int tid = threadIdx.x;
    const int lane = tid & 63;
    const int wv   = tid >> 6;

    __shared__ int idx_s[128];
    __shared__ unsigned short A_s[128 * 40];
    __shared__ unsigned short B_s[128 * 40];

    if (tid < 128) idx_s[tid] = item_seq[m_tile * 128 + tid];
    __syncthreads();

    int myrow[4], myc4[4], myidx[4];
    #pragma unroll
    for (int j = 0; j < 4; ++j) {
        int chunk = tid + 256 * j;
        myrow[j] = chunk >> 3;
        myc4[j]  = chunk & 7;
        myidx[j] = idx_s[myrow[j]];
    }

    f32x4 acc[2][8];
    #pragma unroll
    for (int mi = 0; mi < 2; ++mi)
        #pragma unroll
        for (int ni = 0; ni < 8; ++ni)
            acc[mi][ni] = (f32x4){0.f, 0.f, 0.f, 0.f};

    for (int bk = 0; bk < 16; ++bk) {
        int k0 = bk * 32;
        #pragma unroll
        for (int j = 0; j < 4; ++j) {
            int row = myrow[j], c4 = myc4[j];
            ushort4 ap;
            if (k0 < 256) {
                long pos = (long)m_tile * 128 + row;
                ap = *(const ushort4*)(Rws + pos * 256 + k0 + c4 * 4);
            } else {
                ap = *(const ushort4*)(k_bf + (long)myidx[j] * DK + (k0 - 256) + c4 * 4);
            }
            *(ushort4*)&A_s[row * 40 + c4 * 4] = ap;
            *(ushort4*)&B_s[row * 40 + c4 * 4] =
                *(const ushort4*)(fW_bf + (long)(nt * 128 + row) * 512 + k0 + c4 * 4);
        }
        __syncthreads();

        const int kq = lane >> 4;
        const int rr = lane & 15;
        bf16x8 af[2], bfr[8];
        #pragma unroll
        for (int mi = 0; mi < 2; ++mi)
            af[mi] = *(const bf16x8*)&A_s[(wv * 32 + mi * 16 + rr) * 40 + kq * 8];
        #pragma unroll
        for (int ni = 0; ni < 8; ++ni)
            bfr[ni] = *(const bf16x8*)&B_s[(ni * 16 + rr) * 40 + kq * 8];
        #pragma unroll
        for (int ni = 0; ni < 8; ++ni)
            #pragma unroll
            for (int mi = 0; mi < 2; ++mi)
                acc[mi][ni] = __builtin_amdgcn_mfma_f32_16x16x32_bf16(
                    af[mi], bfr[ni], acc[mi][ni], 0, 0, 0);
        __syncthreads();
    }

    const int rowbase = m_tile * 128 + wv * 32;
    const int cgrp = lane >> 4;
    const int cc   = lane & 15;

    float pw[8];
    #pragma unroll
    for (int ni = 0; ni < 8; ++ni) pw[ni] = p_W[nt * 128 + ni * 16 + cc];

    float s[2][4] = {{0.f,0.f,0.f,0.f},{0.f,0.f,0.f,0.f}};
    #pragma unroll
    for (int ni = 0; ni < 8; ++ni) {
        float bb = f_b[nt * 128 + ni * 16 + cc];
        #pragma unroll
        for (int mi = 0; mi < 2; ++mi)
            #pragma unroll
            for (int i = 0; i < 4; ++i)
                s[mi][i] += fast_tanh(acc[mi][ni][i] + bb) * pw[ni];
    }
    // reduce across the 16-lane col group
    #pragma unroll
    for (int mi = 0; mi < 2; ++mi)
        #pragma unroll
        for (int i = 0; i < 4; ++i) {
            float v = s[mi][i];
            v += __shfl_xor(v, 1); v += __shfl_xor(v, 2);
            v += __shfl_xor(v, 4); v += __shfl_xor(v, 8);
            s[mi][i] = v;
        }
    if (cc == 0) {
        #pragma unroll
        for (int mi = 0; mi < 2; ++mi)
            #pragma unroll
            for (int i = 0; i < 4; ++i)
                pd[(long)nt * BT + rowbase + mi * 16 + cgrp * 4 + i] = s[mi][i];
    }
}

// ---------------------------------------------------------------------------
// K4: out = sigmoid(pd[0][row] + pd[1][row] + p_b)
// ---------------------------------------------------------------------------
__global__ __launch_bounds__(256) void k4_pred(
    const float* __restrict__ pd, const float* __restrict__ p_b,
    float* __restrict__ out)
{
    int i = blockIdx.x * 256 + threadIdx.x;
    out[i] = fast_sigmoid(pd[i] + pd[BT + i] + p_b[0]);
}

// ---------------------------------------------------------------------------
extern "C" void kernel_launch(void* const* d_in, const int* in_sizes, int n_in,
                              void* d_out, int out_size, void* d_ws, size_t ws_size,
                              hipStream_t stream)
{
    const int*   item_seq    = (const int*)d_in[0];
    const int*   correct_seq = (const int*)d_in[1];
    const float* k_emb = (const float*)d_in[2];
    const float* v_emb = (const float*)d_in[3];
    const float* Mk    = (const float*)d_in[4];
    const float* Mv0   = (const float*)d_in[5];
    const float* e_W   = (const float*)d_in[6];
    const float* e_b   = (const float*)d_in[7];
    const float* a_W   = (const float*)d_in[8];
    const float* a_b   = (const float*)d_in[9];
    const float* f_W   = (const float*)d_in[10];
    const float* f_b   = (const float*)d_in[11];
    const float* p_W   = (const float*)d_in[12];
    const float* p_b   = (const float*)d_in[13];
    float* out = (float*)d_out;

    // ws layout (bytes):
    //   [0,   32M)  Wws  w f16 [BT][128]       (k3 tables re-use after k2)
    //   [32M, 160M) EA   f16 [BT][256][{-e,a}] (dead after k2; pd parked here)
    //   [160M,224M) Rws  reads bf16 [BT][256]  (k1 bf16 tables live here pre-k2)
    char* ws = (char*)d_ws;
    unsigned short* Wws = (unsigned short*)(ws);
    unsigned short* EAo = (unsigned short*)(ws + 33554432ll);
    unsigned int*   EAi = (unsigned int*)(ws + 33554432ll);
    unsigned short* Rws = (unsigned short*)(ws + 167772160ll);
    float*          pd  = (float*)(ws + 33554432ll);   // EA region, dead after k2

    // k1-phase bf16 tables, parked in the (still dead) Rws region
    unsigned short* kA_bf = Rws;                 // 512000
    unsigned short* v_bf  = Rws + 512000;        // 1024000
    unsigned short* Mk_bf = Rws + 1536000;       // 32768
    unsigned short* eW_bf = Rws + 1568768;       // 65536
    unsigned short* aW_bf = Rws + 1634304;       // 65536
    // k3-phase bf16 tables, parked in the (dead after k2) Wws region
    unsigned short* k3_bf = Wws;                 // 512000
    unsigned short* fW_bf = Wws + 512000;        // 131072

    k0_cvt<<<dim3(1000, 5), dim3(256), 0, stream>>>(
        k_emb, v_emb, Mk, e_W, a_W,
        kA_bf, v_bf, Mk_bf, eW_bf, aW_bf,
        512000, 1024000, 32768, 65536, 65536);

    k1_wea<<<dim3(1024, 5), dim3(256), 0, stream>>>(
        item_seq, correct_seq, kA_bf, v_bf, Mk_bf, eW_bf, e_b, aW_bf, a_b,
        Wws, EAo);

    k2_scan<<<dim3(256), dim3(256), 0, stream>>>(Mv0, Wws, EAi, Rws);

    k0_cvt<<<dim3(500, 2), dim3(256), 0, stream>>>(
        k_emb, f_W, nullptr, nullptr, nullptr,
        k3_bf, fW_bf, nullptr, nullptr, nullptr,
        512000, 131072, 0, 0, 0);

    k3_f<<<dim3(1024, 2), dim3(256), 0, stream>>>(
        item_seq, k3_bf, fW_bf, f_b, p_W, Rws, pd);

    k4_pred<<<dim3(512), dim3(256), 0, stream>>>(pd, p_b, out);
}

// Round 11
// 442.511 us; speedup vs baseline: 1.1236x; 1.1065x over previous
//
#include <hip/hip_runtime.h>
#include <hip/hip_bf16.h>
#include <hip/hip_fp16.h>

// DKVMN fused pipeline for MI355X (gfx950)
// B=256, T=512, DIM_KEY=256, DIM_VALUE=128, NUM_ITEM=2000
// k0_cvt : f32 tables -> bf16 tables in ws (MFMA operands)
// k1_wea : gather + [Mk|e_W|a_W] GEMM (bf16 MFMA); outputs w (f16 [pos][128])
//          and EA (f16 interleaved [pos][k][{-e, a}])
// k2_scan: scan, M in MFMA B-fragment layout; read = w^T M on the matrix pipe
//          (v-sum inside MFMA accumulate; no LDS/barriers/readlane).
//          R11: R8 partitioning (best measured: 512 blocks = (batch,k-half),
//          4 waves, 2 waves/SIMD) + DISTANCE-4 prefetch (R8's dist-2 covered
//          ~584cy < HBM ~900cy; R9 k-split and R10 batch-pair both regressed).
// k3_f   : [reads|k] @ f_W^T GEMM + tanh, FUSED predict-dot epilogue -> pd
// k4_pred: out = sigmoid(pd[0]+pd[1]+p_b)

#define T_SEQ 512
#define DK    256
#define DV    128
#define NITEM 2000
#define BT    131072   // 256*512

typedef __attribute__((ext_vector_type(8))) short bf16x8;
typedef __attribute__((ext_vector_type(4))) float f32x4;
typedef _Float16 f16x8 __attribute__((ext_vector_type(8)));

__device__ __forceinline__ float bf2f(unsigned short u) {
    return __uint_as_float(((unsigned int)u) << 16);
}
__device__ __forceinline__ unsigned short f2bf(float x) {   // RNE f32->bf16
    unsigned int u = __float_as_uint(x);
    return (unsigned short)((u + 0x7fffu + ((u >> 16) & 1u)) >> 16);
}
__device__ __forceinline__ unsigned short f2h(float x) {    // f32->f16
    _Float16 h = (_Float16)x;
    return __builtin_bit_cast(unsigned short, h);
}
__device__ __forceinline__ float fast_rcp(float x) { return __builtin_amdgcn_rcpf(x); }
__device__ __forceinline__ float fast_sigmoid(float x) { return fast_rcp(1.f + __expf(-x)); }
__device__ __forceinline__ float fast_tanh(float x) {
    float t = __expf(2.f * x);
    return (t - 1.f) * fast_rcp(t + 1.f);
}
__device__ __forceinline__ f16x8 fma8(f16x8 a, f16x8 b, f16x8 c) {
    return __builtin_elementwise_fma(a, b, c);
}
__device__ __forceinline__ f16x8 splat8(_Float16 x) {
    return (f16x8){x, x, x, x, x, x, x, x};
}
__device__ __forceinline__ _Float16 lo16(unsigned int u) {
    return __builtin_bit_cast(_Float16, (unsigned short)(u & 0xffffu));
}
__device__ __forceinline__ _Float16 hi16(unsigned int u) {
    return __builtin_bit_cast(_Float16, (unsigned short)(u >> 16));
}

// ---------------------------------------------------------------------------
// k0: f32 -> bf16 table conversion (up to 5 tables per launch, y = table id)
// ---------------------------------------------------------------------------
__global__ __launch_bounds__(256) void k0_cvt(
    const float* __restrict__ s0, const float* __restrict__ s1,
    const float* __restrict__ s2, const float* __restrict__ s3,
    const float* __restrict__ s4,
    unsigned short* __restrict__ d0, unsigned short* __restrict__ d1,
    unsigned short* __restrict__ d2, unsigned short* __restrict__ d3,
    unsigned short* __restrict__ d4,
    int n0, int n1, int n2, int n3, int n4)
{
    const float* s; unsigned short* d; int n;
    switch (blockIdx.y) {
        case 0:  s = s0; d = d0; n = n0; break;
        case 1:  s = s1; d = d1; n = n1; break;
        case 2:  s = s2; d = d2; n = n2; break;
        case 3:  s = s3; d = d3; n = n3; break;
        default: s = s4; d = d4; n = n4; break;
    }
    int i4 = (blockIdx.x * 256 + threadIdx.x) * 4;
    if (i4 < n) {
        float4 v = *(const float4*)(s + i4);
        ushort4 o;
        o.x = f2bf(v.x); o.y = f2bf(v.y); o.z = f2bf(v.z); o.w = f2bf(v.w);
        *(ushort4*)(d + i4) = o;
    }
}

// ---------------------------------------------------------------------------
// K1: 128 rows x 128 cols per block, 4 waves stacked by rows.
// n_tile 0 -> w (softmax, f16 [row][128]); 1,2 -> e halves (-sigmoid into EA
// even slots); 3,4 -> a halves (tanh into EA odd slots).
// ---------------------------------------------------------------------------
__global__ __launch_bounds__(256) void k1_wea(
    const int* __restrict__ item_seq, const int* __restrict__ correct_seq,
    const unsigned short* __restrict__ k_bf, const unsigned short* __restrict__ v_bf,
    const unsigned short* __restrict__ Mk_bf,
    const unsigned short* __restrict__ eW_bf, const float* __restrict__ e_b,
    const unsigned short* __restrict__ aW_bf, const float* __restrict__ a_b,
    unsigned short* __restrict__ Wout, unsigned short* __restrict__ EAout)
{
    const int m_tile = blockIdx.x;   // 0..1023
    const int n_tile = blockIdx.y;   // 0..4
    const int tid  = threadIdx.x;
    const int lane = tid & 63;
    const int wv   = tid >> 6;

    __shared__ int idx_s[128];
    __shared__ unsigned short A_s[128 * 40];
    __shared__ unsigned short B_s[128 * 40];

    const unsigned short* Atab = (n_tile == 0) ? k_bf : v_bf;
    const unsigned short* Wtab; int wrow0;
    if (n_tile == 0)      { Wtab = Mk_bf; wrow0 = 0;   }
    else if (n_tile == 1) { Wtab = eW_bf; wrow0 = 0;   }
    else if (n_tile == 2) { Wtab = eW_bf; wrow0 = 128; }
    else if (n_tile == 3) { Wtab = aW_bf; wrow0 = 0;   }
    else                  { Wtab = aW_bf; wrow0 = 128; }

    if (tid < 128) {
        int pos = m_tile * 128 + tid;
        int it = item_seq[pos];
        int co = correct_seq[pos];
        idx_s[tid] = (n_tile == 0) ? it : (it + NITEM * co);
    }
    __syncthreads();

    int myrow[4], myc4[4], myidx[4];
    #pragma unroll
    for (int j = 0; j < 4; ++j) {
        int chunk = tid + 256 * j;
        myrow[j] = chunk >> 3;
        myc4[j]  = chunk & 7;
        myidx[j] = idx_s[myrow[j]];
    }

    f32x4 acc[2][8];
    #pragma unroll
    for (int mi = 0; mi < 2; ++mi)
        #pragma unroll
        for (int ni = 0; ni < 8; ++ni)
            acc[mi][ni] = (f32x4){0.f, 0.f, 0.f, 0.f};

    for (int bk = 0; bk < 8; ++bk) {
        int k0 = bk * 32;
        #pragma unroll
        for (int j = 0; j < 4; ++j) {
            int row = myrow[j], c4 = myc4[j];
            *(ushort4*)&A_s[row * 40 + c4 * 4] =
                *(const ushort4*)(Atab + (long)myidx[j] * DK + k0 + c4 * 4);
            *(ushort4*)&B_s[row * 40 + c4 * 4] =
                *(const ushort4*)(Wtab + (long)(wrow0 + row) * DK + k0 + c4 * 4);
        }
        __syncthreads();

        const int kq = lane >> 4;   // k-slot 0..3 (8 bf16 each)
        const int rr = lane & 15;
        bf16x8 af[2], bfr[8];
        #pragma unroll
        for (int mi = 0; mi < 2; ++mi)
            af[mi] = *(const bf16x8*)&A_s[(wv * 32 + mi * 16 + rr) * 40 + kq * 8];
        #pragma unroll
        for (int ni = 0; ni < 8; ++ni)
            bfr[ni] = *(const bf16x8*)&B_s[(ni * 16 + rr) * 40 + kq * 8];
        #pragma unroll
        for (int ni = 0; ni < 8; ++ni)
            #pragma unroll
            for (int mi = 0; mi < 2; ++mi)
                acc[mi][ni] = __builtin_amdgcn_mfma_f32_16x16x32_bf16(
                    af[mi], bfr[ni], acc[mi][ni], 0, 0, 0);
        __syncthreads();
    }

    // C/D layout: col = lane&15, row = (lane>>4)*4 + reg (m89-verified)
    const int rowbase = m_tile * 128 + wv * 32;
    const int cgrp = lane >> 4;
    const int cc   = lane & 15;

    if (n_tile == 0) {
        #pragma unroll
        for (int mi = 0; mi < 2; ++mi) {
            #pragma unroll
            for (int i = 0; i < 4; ++i) {
                float m = -1e30f;
                #pragma unroll
                for (int ni = 0; ni < 8; ++ni) m = fmaxf(m, acc[mi][ni][i]);
                m = fmaxf(m, __shfl_xor(m, 1));
                m = fmaxf(m, __shfl_xor(m, 2));
                m = fmaxf(m, __shfl_xor(m, 4));
                m = fmaxf(m, __shfl_xor(m, 8));
                float p[8]; float s = 0.f;
                #pragma unroll
                for (int ni = 0; ni < 8; ++ni) { p[ni] = __expf(acc[mi][ni][i] - m); s += p[ni]; }
                s += __shfl_xor(s, 1); s += __shfl_xor(s, 2);
                s += __shfl_xor(s, 4); s += __shfl_xor(s, 8);
                float inv = fast_rcp(s);
                int row = rowbase + mi * 16 + cgrp * 4 + i;
                #pragma unroll
                for (int ni = 0; ni < 8; ++ni)
                    Wout[(long)row * 128 + ni * 16 + cc] = f2h(p[ni] * inv);
            }
        }
    } else {
        const bool is_e = (n_tile <= 2);
        const float* bias = is_e ? e_b : a_b;
        const int colbase = (is_e ? (n_tile - 1) : (n_tile - 3)) * 128;
        const int sel = is_e ? 0 : 1;
        #pragma unroll
        for (int ni = 0; ni < 8; ++ni) {
            int colp = colbase + ni * 16 + cc;
            float bb = bias[colp];
            #pragma unroll
            for (int mi = 0; mi < 2; ++mi) {
                #pragma unroll
                for (int i = 0; i < 4; ++i) {
                    int row = rowbase + mi * 16 + cgrp * 4 + i;
                    float x = acc[mi][ni][i] + bb;
                    float v = is_e ? -fast_sigmoid(x) : fast_tanh(x);  // e stored negated
                    EAout[(long)row * 512 + 2 * colp + sel] = f2h(v);
                }
            }
        }
    }
}

// ---------------------------------------------------------------------------
// K2: scan, MFMA-offloaded reads. 512 blocks = (batch, k-half) = 2 blocks/CU,
// 256 thr = 4 waves = 2 waves/SIMD. 0 LDS, 0 barriers. Wave owns 128v x 32k.
// M in B-fragment layout of mfma_f32_16x16x32_f16:
//   Mb[vt][kt][j] = M[v = vt*32 + (lane>>4)*8 + j][k = kw + kt*16 + (lane&15)]
// Per step: 4 w-frag loads (A-operand AND packed update multiplier), 2 EA
// dwords; 8 accumulating MFMAs -> read (pre-update M, D only stored); VALU
// update = 16 fma8. DISTANCE-4 prefetch, named sets A..D (R5: no big arrays;
// launch_bounds(256,2) caps regs at 256 -- grid-limited to 2 waves/SIMD
// anyway, so the higher cap costs nothing and avoids spill).
// ---------------------------------------------------------------------------
__global__ __launch_bounds__(256, 2) void k2_scan(
    const float* __restrict__ Mv0,
    const unsigned short* __restrict__ Wws,
    const unsigned int* __restrict__ EAws,
    unsigned short* __restrict__ Rws)
{
    const int b    = blockIdx.x >> 1;
    const int kh   = blockIdx.x & 1;
    const int tid  = threadIdx.x;
    const int lane = tid & 63;
    const int wv   = tid >> 6;          // 0..3
    const int row16 = lane & 15;
    const int oct   = lane >> 4;        // v-octet within each 32-v tile
    const int kw    = kh * 128 + wv * 32;

    // M fragments (one-time f32 gather)
    f16x8 Mb[4][2];
    #pragma unroll
    for (int vt = 0; vt < 4; ++vt)
        #pragma unroll
        for (int kt = 0; kt < 2; ++kt) {
            f16x8 m;
            #pragma unroll
            for (int j = 0; j < 8; ++j)
                m[j] = (_Float16)Mv0[(vt * 32 + oct * 8 + j) * DK + kw + kt * 16 + row16];
            Mb[vt][kt] = m;
        }

    const long pos0 = (long)b * T_SEQ;

    // distance-4 prefetch: named sets A..D (constant indices only)
    uint4 wfA[4], wfB[4], wfC[4], wfD[4];
    unsigned int eaA0, eaA1, eaB0, eaB1, eaC0, eaC1, eaD0, eaD1;
#define K2_LOAD(PT, WF, EA0, EA1)                                              \
    {                                                                          \
        const unsigned short* wq = Wws + (PT) * 128 + oct * 8;                 \
        WF[0] = *(const uint4*)(wq);                                           \
        WF[1] = *(const uint4*)(wq + 32);                                      \
        WF[2] = *(const uint4*)(wq + 64);                                      \
        WF[3] = *(const uint4*)(wq + 96);                                      \
        EA0 = EAws[(PT) * 256 + kw + row16];                                   \
        EA1 = EAws[(PT) * 256 + kw + 16 + row16];                              \
    }
    K2_LOAD(pos0 + 0, wfA, eaA0, eaA1)
    K2_LOAD(pos0 + 1, wfB, eaB0, eaB1)
    K2_LOAD(pos0 + 2, wfC, eaC0, eaC1)
    K2_LOAD(pos0 + 3, wfD, eaD0, eaD1)

#define K2_STEP(T, WF, EA0, EA1)                                               \
    {                                                                          \
        const uint4 w0 = WF[0], w1 = WF[1], w2 = WF[2], w3 = WF[3];            \
        const unsigned int ea0 = EA0, ea1 = EA1;                               \
        {   /* issue t+4 loads: ~4 bodies (~1170cy) of latency cover */        \
            long pn = pos0 + ((T) + 4 < T_SEQ ? (T) + 4 : T_SEQ - 1);          \
            K2_LOAD(pn, WF, EA0, EA1)                                          \
        }                                                                      \
        const f16x8 w80 = __builtin_bit_cast(f16x8, w0);                       \
        const f16x8 w81 = __builtin_bit_cast(f16x8, w1);                       \
        const f16x8 w82 = __builtin_bit_cast(f16x8, w2);                       \
        const f16x8 w83 = __builtin_bit_cast(f16x8, w3);                       \
        /* read on the matrix pipe, pre-update M (D not consumed by loop) */   \
        f32x4 D0 = (f32x4){0.f, 0.f, 0.f, 0.f};                                \
        f32x4 D1 = (f32x4){0.f, 0.f, 0.f, 0.f};                                \
        D0 = __builtin_amdgcn_mfma_f32_16x16x32_f16(w80, Mb[0][0], D0, 0,0,0); \
        D0 = __builtin_amdgcn_mfma_f32_16x16x32_f16(w81, Mb[1][0], D0, 0,0,0); \
        D0 = __builtin_amdgcn_mfma_f32_16x16x32_f16(w82, Mb[2][0], D0, 0,0,0); \
        D0 = __builtin_amdgcn_mfma_f32_16x16x32_f16(w83, Mb[3][0], D0, 0,0,0); \
        D1 = __builtin_amdgcn_mfma_f32_16x16x32_f16(w80, Mb[0][1], D1, 0,0,0); \
        D1 = __builtin_amdgcn_mfma_f32_16x16x32_f16(w81, Mb[1][1], D1, 0,0,0); \
        D1 = __builtin_amdgcn_mfma_f32_16x16x32_f16(w82, Mb[2][1], D1, 0,0,0); \
        D1 = __builtin_amdgcn_mfma_f32_16x16x32_f16(w83, Mb[3][1], D1, 0,0,0); \
        /* VALU update: M = M + w*(a - e*M); EA holds {-e, a} */               \
        const f16x8 ne80 = splat8(lo16(ea0)), a80 = splat8(hi16(ea0));         \
        const f16x8 ne81 = splat8(lo16(ea1)), a81 = splat8(hi16(ea1));         \
        Mb[0][0] = fma8(w80, fma8(ne80, Mb[0][0], a80), Mb[0][0]);             \
        Mb[1][0] = fma8(w81, fma8(ne80, Mb[1][0], a80), Mb[1][0]);             \
        Mb[2][0] = fma8(w82, fma8(ne80, Mb[2][0], a80), Mb[2][0]);             \
        Mb[3][0] = fma8(w83, fma8(ne80, Mb[3][0], a80), Mb[3][0]);             \
        Mb[0][1] = fma8(w80, fma8(ne81, Mb[0][1], a81), Mb[0][1]);             \
        Mb[1][1] = fma8(w81, fma8(ne81, Mb[1][1], a81), Mb[1][1]);             \
        Mb[2][1] = fma8(w82, fma8(ne81, Mb[2][1], a81), Mb[2][1]);             \
        Mb[3][1] = fma8(w83, fma8(ne81, Mb[3][1], a81), Mb[3][1]);             \
        /* store read: all D rows identical (A rows = w for every row) */      \
        if (lane < 16) {                                                       \
            unsigned short* rp = Rws + (pos0 + (T)) * 256 + kw + lane;         \
            rp[0]  = f2bf(D0[0]);                                              \
            rp[16] = f2bf(D1[0]);                                              \
        }                                                                      \
    }

    for (int t = 0; t < T_SEQ; t += 4) {
        K2_STEP(t,     wfA, eaA0, eaA1)
        K2_STEP(t + 1, wfB, eaB0, eaB1)
        K2_STEP(t + 2, wfC, eaC0, eaC1)
        K2_STEP(t + 3, wfD, eaD0, eaD1)
    }
#undef K2_STEP
#undef K2_LOAD
}

// ---------------------------------------------------------------------------
// K3: f = tanh([reads | k] @ f_W^T + f_b), fused predict-dot epilogue:
// writes pd[nt][row] = sum_{cols in tile} f * p_W  (f itself never stored).
// ---------------------------------------------------------------------------
__global__ __launch_bounds__(256) void k3_f(
    const int* __restrict__ item_seq,
    const unsigned short* __restrict__ k_bf,
    const unsigned short* __restrict__ fW_bf, const float* __restrict__ f_b,
    const float* __restrict__ p_W,
    const unsigned short* __restrict__ Rws,
    float* __restrict__ pd)
{
    const int m_tile = blockIdx.x;   // 0..1023
    const int nt  = blockIdx.y;      // 0..1
    const int tid = threadIdx.x;
    const int lane = tid & 63;
    const int wv   = tid >> 6;

    __shared__ int idx_s[128];
    __shared__ unsigned short A_s[128 * 40];
    __shared__ unsigned short B_s[128 * 40];

    if (tid < 128) idx_s[tid] = item_seq[m_tile * 128 + tid];
    __syncthreads();

    int myrow[4], myc4[4], myidx[4];
    #pragma unroll
    for (int j = 0; j < 4; ++j) {
        int chunk = tid + 256 * j;
        myrow[j] = chunk >> 3;
        myc4[j]  = chunk & 7;
        myidx[j] = idx_s[myrow[j]];
    }

    f32x4 acc[2][8];
    #pragma unroll
    for (int mi = 0; mi < 2; ++mi)
        #pragma unroll
        for (int ni = 0; ni < 8; ++ni)
            acc[mi][ni] = (f32x4){0.f, 0.f, 0.f, 0.f};

    for (int bk = 0; bk < 16; ++bk) {
        int k0 = bk * 32;
        #pragma unroll
        for (int j = 0; j < 4; ++j) {
            int row = myrow[j], c4 = myc4[j];
            ushort4 ap;
            if (k0 < 256) {
                long pos = (long)m_tile * 128 + row;
                ap = *(const ushort4*)(Rws + pos * 256 + k0 + c4 * 4);
            } else {
                ap = *(const ushort4*)(k_bf + (long)myidx[j] * DK + (k0 - 256) + c4 * 4);
            }
            *(ushort4*)&A_s[row * 40 + c4 * 4] = ap;
            *(ushort4*)&B_s[row * 40 + c4 * 4] =
                *(const ushort4*)(fW_bf + (long)(nt * 128 + row) * 512 + k0 + c4 * 4);
        }
        __syncthreads();

        const int kq = lane >> 4;
        const int rr = lane & 15;
        bf16x8 af[2], bfr[8];
        #pragma unroll
        for (int mi = 0; mi < 2; ++mi)
            af[mi] = *(const bf16x8*)&A_s[(wv * 32 + mi * 16 + rr) * 40 + kq * 8];
        #pragma unroll
        for (int ni = 0; ni < 8; ++ni)
            bfr[ni] = *(const bf16x8*)&B_s[(ni * 16 + rr) * 40 + kq * 8];
        #pragma unroll
        for (int ni = 0; ni < 8; ++ni)
            #pragma unroll
            for (int mi = 0; mi < 2; ++mi)
                acc[mi][ni] = __builtin_amdgcn_mfma_f32_16x16x32_bf16(
                    af[mi], bfr[ni], acc[mi][ni], 0, 0, 0);
        __syncthreads();
    }

    const int rowbase = m_tile * 128 + wv * 32;
    const int cgrp = lane >> 4;
    const int cc   = lane & 15;

    float pw[8];
    #pragma unroll
    for (int ni = 0; ni < 8; ++ni) pw[ni] = p_W[nt * 128 + ni * 16 + cc];

    float s[2][4] = {{0.f,0.f,0.f,0.f},{0.f,0.f,0.f,0.f}};
    #pragma unroll
    for (int ni = 0; ni < 8; ++ni) {
        float bb = f_b[nt * 128 + ni * 16 + cc];
        #pragma unroll
        for (int mi = 0; mi < 2; ++mi)
            #pragma unroll
            for (int i = 0; i < 4; ++i)
                s[mi][i] += fast_tanh(acc[mi][ni][i] + bb) * pw[ni];
    }
    // reduce across the 16-lane col group
    #pragma unroll
    for (int mi = 0; mi < 2; ++mi)
        #pragma unroll
        for (int i = 0; i < 4; ++i) {
            float v = s[mi][i];
            v += __shfl_xor(v, 1); v += __shfl_xor(v, 2);
            v += __shfl_xor(v, 4); v += __shfl_xor(v, 8);
            s[mi][i] = v;
        }
    if (cc == 0) {
        #pragma unroll
        for (int mi = 0; mi < 2; ++mi)
            #pragma unroll
            for (int i = 0; i < 4; ++i)
                pd[(long)nt * BT + rowbase + mi * 16 + cgrp * 4 + i] = s[mi][i];
    }
}

// ---------------------------------------------------------------------------
// K4: out = sigmoid(pd[0][row] + pd[1][row] + p_b)
// ---------------------------------------------------------------------------
__global__ __launch_bounds__(256) void k4_pred(
    const float* __restrict__ pd, const float* __restrict__ p_b,
    float* __restrict__ out)
{
    int i = blockIdx.x * 256 + threadIdx.x;
    out[i] = fast_sigmoid(pd[i] + pd[BT + i] + p_b[0]);
}

// ---------------------------------------------------------------------------
extern "C" void kernel_launch(void* const* d_in, const int* in_sizes, int n_in,
                              void* d_out, int out_size, void* d_ws, size_t ws_size,
                              hipStream_t stream)
{
    const int*   item_seq    = (const int*)d_in[0];
    const int*   correct_seq = (const int*)d_in[1];
    const float* k_emb = (const float*)d_in[2];
    const float* v_emb = (const float*)d_in[3];
    const float* Mk    = (const float*)d_in[4];
    const float* Mv0   = (const float*)d_in[5];
    const float* e_W   = (const float*)d_in[6];
    const float* e_b   = (const float*)d_in[7];
    const float* a_W   = (const float*)d_in[8];
    const float* a_b   = (const float*)d_in[9];
    const float* f_W   = (const float*)d_in[10];
    const float* f_b   = (const float*)d_in[11];
    const float* p_W   = (const float*)d_in[12];
    const float* p_b   = (const float*)d_in[13];
    float* out = (float*)d_out;

    // ws layout (bytes):
    //   [0,   32M)  Wws  w f16 [BT][128]       (k3 tables re-use after k2)
    //   [32M, 160M) EA   f16 [BT][256][{-e,a}] (dead after k2; pd parked here)
    //   [160M,224M) Rws  reads bf16 [BT][256]  (k1 bf16 tables live here pre-k2)
    char* ws = (char*)d_ws;
    unsigned short* Wws = (unsigned short*)(ws);
    unsigned short* EAo = (unsigned short*)(ws + 33554432ll);
    unsigned int*   EAi = (unsigned int*)(ws + 33554432ll);
    unsigned short* Rws = (unsigned short*)(ws + 167772160ll);
    float*          pd  = (float*)(ws + 33554432ll);   // EA region, dead after k2

    // k1-phase bf16 tables, parked in the (still dead) Rws region
    unsigned short* kA_bf = Rws;                 // 512000
    unsigned short* v_bf  = Rws + 512000;        // 1024000
    unsigned short* Mk_bf = Rws + 1536000;       // 32768
    unsigned short* eW_bf = Rws + 1568768;       // 65536
    unsigned short* aW_bf = Rws + 1634304;       // 65536
    // k3-phase bf16 tables, parked in the (dead after k2) Wws region
    unsigned short* k3_bf = Wws;                 // 512000
    unsigned short* fW_bf = Wws + 512000;        // 131072

    k0_cvt<<<dim3(1000, 5), dim3(256), 0, stream>>>(
        k_emb, v_emb, Mk, e_W, a_W,
        kA_bf, v_bf, Mk_bf, eW_bf, aW_bf,
        512000, 1024000, 32768, 65536, 65536);

    k1_wea<<<dim3(1024, 5), dim3(256), 0, stream>>>(
        item_seq, correct_seq, kA_bf, v_bf, Mk_bf, eW_bf, e_b, aW_bf, a_b,
        Wws, EAo);

    k2_scan<<<dim3(512), dim3(256), 0, stream>>>(Mv0, Wws, EAi, Rws);

    k0_cvt<<<dim3(500, 2), dim3(256), 0, stream>>>(
        k_emb, f_W, nullptr, nullptr, nullptr,
        k3_bf, fW_bf, nullptr, nullptr, nullptr,
        512000, 131072, 0, 0, 0);

    k3_f<<<dim3(1024, 2), dim3(256), 0, stream>>>(
        item_seq, k3_bf, fW_bf, f_b, p_W, Rws, pd);

    k4_pred<<<dim3(512), dim3(256), 0, stream>>>(pd, p_b, out);
}